// Round 8
// baseline (348.087 us; speedup 1.0000x reference)
//
#include <hip/hip_runtime.h>
#include <math.h>

#define BB 2
#define SS 2048
#define DD 1024
#define NH 16
#define HDM 64
#define RNK 8

typedef short short8 __attribute__((ext_vector_type(8)));
typedef float floatx4 __attribute__((ext_vector_type(4)));

static __device__ __forceinline__ ushort f2bf(float f) {
  union { float f; unsigned u; } v;
  v.f = f;
  unsigned r = (v.u + 0x7FFFu + ((v.u >> 16) & 1u)) >> 16;
  return (ushort)r;
}
static __device__ __forceinline__ float bf2f(ushort u) {
  union { unsigned u; float f; } v;
  v.u = ((unsigned)u) << 16;
  return v.f;
}
static __device__ __forceinline__ unsigned pack_bf_trunc(float a, float b) {
  union { float f; unsigned u; } x, y;
  x.f = a;
  y.f = b;
  return __builtin_amdgcn_perm(y.u, x.u, 0x07060302u);
}
static __device__ __forceinline__ unsigned pack_bf_rne(float a, float b) {
  union { float f; unsigned u; } x, y;
  x.f = a;
  y.f = b;
  unsigned xu = x.u + 0x7FFFu + ((x.u >> 16) & 1u);
  unsigned yu = y.u + 0x7FFFu + ((y.u >> 16) & 1u);
  return __builtin_amdgcn_perm(yu, xu, 0x07060302u);
}

// ---------------------------------------------------------------------------
// prep_all: one launch, 4 independent jobs partitioned by blockIdx.x
// ---------------------------------------------------------------------------
__global__ __launch_bounds__(256) void prep_all(
    const float* __restrict__ x, const float* __restrict__ Wq,
    const float* __restrict__ Wk, const float* __restrict__ Wv,
    const float* __restrict__ Wo, ushort* __restrict__ xb,
    ushort* __restrict__ Wcat, ushort* __restrict__ Wtk,
    ushort* __restrict__ Wtv, ushort* __restrict__ Wto,
    float2* __restrict__ tab, float* __restrict__ zsum) {
  __shared__ float tile[32][33];
  int blk = blockIdx.x;
  int tid = threadIdx.x;
  if (blk < 4096) {
    int gid = blk * 256 + tid;
    float4 a = ((const float4*)x)[gid];
    ushort4 o;
    o.x = f2bf(a.x);
    o.y = f2bf(a.y);
    o.z = f2bf(a.z);
    o.w = f2bf(a.w);
    ((ushort4*)xb)[gid] = o;
  } else if (blk < 8192) {
    int local = blk - 4096;
    int which = local >> 10;
    const float* W = which == 0 ? Wq : which == 1 ? Wk : which == 2 ? Wv : Wo;
    ushort* Wt = which == 0 ? Wcat : which == 1 ? Wtk : which == 2 ? Wtv : Wto;
    int t = local & 1023;
    int bx = t & 31, by = t >> 5;
    int tx = tid & 31, ty = tid >> 5;
#pragma unroll
    for (int i = 0; i < 4; ++i)
      tile[ty + 8 * i][tx] =
          W[(size_t)(by * 32 + ty + 8 * i) * DD + bx * 32 + tx];
    __syncthreads();
#pragma unroll
    for (int i = 0; i < 4; ++i)
      Wt[(size_t)(bx * 32 + ty + 8 * i) * DD + by * 32 + tx] =
          f2bf(tile[tx][ty + 8 * i]);
  } else if (blk < 8448) {
    int gid = (blk - 8192) * 256 + tid;
    int i = gid >> 11, s = gid & 2047;
    float freq = expf(-(float)i * (9.210340371976184f / 32.0f));
    float sn, cn;
    sincosf((float)s * freq, &sn, &cn);
    tab[gid] = make_float2(cn, sn);
  } else {
    int lb = blk - 8448;
    int b = lb >> 7;
    int s0 = (lb & 127) * 16;
    float p0 = 0.f, p1 = 0.f, p2 = 0.f, p3 = 0.f;
    const float* xp = x + ((size_t)b * SS + s0) * DD;
    for (int s = 0; s < 16; ++s) {
      const float* row = xp + (size_t)s * DD;
      p0 += row[tid];
      p1 += row[tid + 256];
      p2 += row[tid + 512];
      p3 += row[tid + 768];
    }
    atomicAdd(&zsum[b * DD + tid], p0);
    atomicAdd(&zsum[b * DD + tid + 256], p1);
    atomicAdd(&zsum[b * DD + tid + 512], p2);
    atomicAdd(&zsum[b * DD + tid + 768], p3);
  }
}

// ---------------------------------------------------------------------------
// gen_h / hyper_c2 / gen_AB / weff  (unchanged)
// ---------------------------------------------------------------------------
__global__ __launch_bounds__(256) void gen_h(
    const float* __restrict__ zsum,
    const float* __restrict__ kw1, const float* __restrict__ vw1,
    float* __restrict__ h_pre) {
  int b = blockIdx.x & 1;
  int p = (blockIdx.x >> 1) & 1;
  int slice = blockIdx.y;
  const float* w1 = p ? vw1 : kw1;
  int tid = threadIdx.x;
  float acc = 0.f;
  int j0 = slice * 128;
  for (int j = j0; j < j0 + 128; ++j) {
    float z = zsum[b * DD + j] * (1.0f / (float)SS);
    acc += z * w1[j * 256 + tid];
  }
  atomicAdd(&h_pre[(p * 2 + b) * 256 + tid], acc);
}

__global__ __launch_bounds__(256) void hyper_c2(
    const float* __restrict__ h_pre,
    const float* __restrict__ kb1, const float* __restrict__ kw2,
    const float* __restrict__ kb2,
    const float* __restrict__ vb1, const float* __restrict__ vw2,
    const float* __restrict__ vb2, float* __restrict__ c_all) {
  int p = blockIdx.x >> 1;
  int b = blockIdx.x & 1;
  const float* b1 = p ? vb1 : kb1;
  const float* w2 = p ? vw2 : kw2;
  const float* b2 = p ? vb2 : kb2;
  __shared__ float hs[256];
  __shared__ float part[256];
  int tid = threadIdx.x;
  float hv = h_pre[(p * 2 + b) * 256 + tid] + b1[tid];
  hs[tid] = hv / (1.0f + expf(-hv));
  __syncthreads();
  int n = tid & 63, chunk = tid >> 6;
  float a = 0.f;
  for (int jj = 0; jj < 64; ++jj) {
    int j = chunk * 64 + jj;
    a += hs[j] * w2[j * 64 + n];
  }
  part[tid] = a;
  __syncthreads();
  if (tid < 64) {
    c_all[(p * 2 + b) * 64 + tid] =
        part[tid] + part[tid + 64] + part[tid + 128] + part[tid + 192] + b2[tid];
  }
}

__global__ __launch_bounds__(256) void gen_AB(
    const float* __restrict__ c_all,
    const float* __restrict__ kgAw, const float* __restrict__ kgAb,
    const float* __restrict__ kgBw, const float* __restrict__ kgBb,
    const float* __restrict__ vgAw, const float* __restrict__ vgAb,
    const float* __restrict__ vgBw, const float* __restrict__ vgBb,
    float* __restrict__ Ak, float* __restrict__ Bk,
    float* __restrict__ Av, float* __restrict__ Bv) {
  int y = blockIdx.y;
  int p = y >> 1, mat = y & 1;
  const float* gw = p ? (mat ? vgBw : vgAw) : (mat ? kgBw : kgAw);
  const float* gb = p ? (mat ? vgBb : vgAb) : (mat ? kgBb : kgAb);
  float* obase = p ? (mat ? Bv : Av) : (mat ? Bk : Ak);

  __shared__ float c0[64], c1[64];
  int tid = threadIdx.x;
  if (tid < 64) c0[tid] = c_all[p * 128 + tid];
  else if (tid < 128) c1[tid - 64] = c_all[p * 128 + tid];
  __syncthreads();

  int idx = blockIdx.x * 256 + tid;
  float a0 = gb[idx], a1 = a0;
#pragma unroll
  for (int j = 0; j < 64; ++j) {
    float w = gw[j * (RNK * DD) + idx];
    a0 += c0[j] * w;
    a1 += c1[j] * w;
  }
  obase[idx] = a0;
  obase[RNK * DD + idx] = a1;
}

__global__ __launch_bounds__(256) void weff(
    const float* __restrict__ Ak, const float* __restrict__ Bk,
    const float* __restrict__ Av, const float* __restrict__ Bv,
    const ushort* __restrict__ Wtk, const ushort* __restrict__ Wtv,
    ushort* __restrict__ Wcat) {
  int y = blockIdx.y;
  int p = y >> 1, b = y & 1;
  const float* A = (p ? Av : Ak) + b * (RNK * DD);
  const float* Bm = (p ? Bv : Bk) + b * (RNK * DD);
  const ushort* src = p ? Wtv : Wtk;
  ushort* dst = Wcat + ((size_t)(1 + 2 * p + b) << 20);

  int tid = threadIdx.x;
  int row = blockIdx.x * 16 + (tid >> 4);
  int cg = tid & 15;
  float bm[RNK];
#pragma unroll
  for (int r = 0; r < RNK; ++r) bm[r] = Bm[row * RNK + r];
  for (int kk = cg * 64; kk < cg * 64 + 64; kk += 4) {
    float4 acc = make_float4(0.f, 0.f, 0.f, 0.f);
#pragma unroll
    for (int r = 0; r < RNK; ++r) {
      float4 a4 = *(const float4*)&A[r * DD + kk];
      acc.x += bm[r] * a4.x;
      acc.y += bm[r] * a4.y;
      acc.z += bm[r] * a4.z;
      acc.w += bm[r] * a4.w;
    }
    ushort4 ws = *(const ushort4*)&src[(size_t)row * DD + kk];
    ushort4 o;
    o.x = f2bf(bf2f(ws.x) + acc.x * 0.125f);
    o.y = f2bf(bf2f(ws.y) + acc.y * 0.125f);
    o.z = f2bf(bf2f(ws.z) + acc.z * 0.125f);
    o.w = f2bf(bf2f(ws.w) + acc.w * 0.125f);
    *(ushort4*)&dst[(size_t)row * DD + kk] = o;
  }
}

// ---------------------------------------------------------------------------
// gemm_qkv (unchanged)
// ---------------------------------------------------------------------------
__global__ __launch_bounds__(256) void gemm_qkv(
    const ushort* __restrict__ Axb, const ushort* __restrict__ Wcat,
    const float* __restrict__ bq, const float* __restrict__ bk,
    const float* __restrict__ bv, const float2* __restrict__ tab,
    ushort* __restrict__ qhb, ushort* __restrict__ khb,
    ushort* __restrict__ vhb) {
  __shared__ ushort As[128][40];
  __shared__ ushort Bs[128][40];
  int tid = threadIdx.x;
  int bm = blockIdx.x * 128;
  int ny = blockIdx.y;
  int path = ny >> 3;
  int nb = (ny & 7) * 128;
  int b_blk = bm >> 11;
  const ushort* Wbase =
      (path == 0) ? Wcat : Wcat + ((size_t)(1 + (path - 1) * 2 + b_blk) << 20);
  const float* bias = (path == 0) ? bq : (path == 1 ? bk : bv);
  ushort* outp = (path == 0) ? qhb : (path == 1 ? khb : vhb);

  int w = tid >> 6, lane = tid & 63, l16 = lane & 15, q4 = lane >> 4;
  int wm = (w >> 1) * 64, wn = (w & 1) * 64;
  floatx4 acc[4][4];
#pragma unroll
  for (int mi = 0; mi < 4; ++mi)
#pragma unroll
    for (int ni = 0; ni < 4; ++ni) acc[mi][ni] = 0;

  int sr = tid >> 2, sc = (tid & 3) * 8;
  const ushort* Ap0 = Axb + (size_t)(bm + sr) * DD + sc;
  const ushort* Ap1 = Axb + (size_t)(bm + sr + 64) * DD + sc;
  const ushort* Bp0 = Wbase + (size_t)(nb + sr) * DD + sc;
  const ushort* Bp1 = Wbase + (size_t)(nb + sr + 64) * DD + sc;

  for (int k0 = 0; k0 < DD; k0 += 32) {
    uint4 a0 = *(const uint4*)(Ap0 + k0);
    uint4 a1 = *(const uint4*)(Ap1 + k0);
    uint4 b0 = *(const uint4*)(Bp0 + k0);
    uint4 b1 = *(const uint4*)(Bp1 + k0);
    __syncthreads();
    *(uint4*)&As[sr][sc] = a0;
    *(uint4*)&As[sr + 64][sc] = a1;
    *(uint4*)&Bs[sr][sc] = b0;
    *(uint4*)&Bs[sr + 64][sc] = b1;
    __syncthreads();
    short8 af[4], bf[4];
#pragma unroll
    for (int mi = 0; mi < 4; ++mi)
      af[mi] = *(const short8*)&As[wm + mi * 16 + l16][q4 * 8];
#pragma unroll
    for (int ni = 0; ni < 4; ++ni)
      bf[ni] = *(const short8*)&Bs[wn + ni * 16 + l16][q4 * 8];
#pragma unroll
    for (int mi = 0; mi < 4; ++mi)
#pragma unroll
      for (int ni = 0; ni < 4; ++ni)
        acc[mi][ni] = __builtin_amdgcn_mfma_f32_16x16x32_bf16(
            af[mi], bf[ni], acc[mi][ni], 0, 0, 0);
  }

  int h = (nb + wn) >> 6;
  float biasv[4];
#pragma unroll
  for (int ni = 0; ni < 4; ++ni) biasv[ni] = bias[nb + wn + ni * 16 + l16];

#pragma unroll
  for (int mi = 0; mi < 4; ++mi) {
#pragma unroll
    for (int r = 0; r < 4; ++r) {
      int grow = bm + wm + mi * 16 + q4 * 4 + r;
      int bb = grow >> 11, s = grow & 2047;
      ushort* orow = outp + (((size_t)(bb * NH + h) * SS + s) << 6);
      float v[4];
#pragma unroll
      for (int ni = 0; ni < 4; ++ni) v[ni] = acc[mi][ni][r] + biasv[ni];
      if (path < 2) {
#pragma unroll
        for (int ni = 0; ni < 2; ++ni) {
          float2 cs = tab[((ni * 16 + l16) << 11) + s];
          float a = v[ni] * cs.x - v[ni + 2] * cs.y;
          float c = v[ni + 2] * cs.x + v[ni] * cs.y;
          v[ni] = a;
          v[ni + 2] = c;
        }
      }
#pragma unroll
      for (int ni = 0; ni < 4; ++ni) orow[ni * 16 + l16] = f2bf(v[ni]);
    }
  }
}

// ---------------------------------------------------------------------------
// attn_split: split-K causal flash attention. Chunk = up to 8 key-tiles.
// No-max softmax => (O,l) partials are plain sums (associative/commutative).
// Single-chunk stripes (s<8) write final bf16 directly to aob2; multi-chunk
// stripes atomicAdd fp32 partials into Oacc[bh][64d][2048s] and Lacc.
// grid 2560 = 80 (s,c)-units (heavy-first) x 32 (b,h). 2 waves x 32 queries.
// ---------------------------------------------------------------------------
#define VT_IDX(d, c) ((unsigned)(72 * (d) + 16 * ((d) >> 3) + (c)))

__global__ __launch_bounds__(128) void attn_split(
    const ushort* __restrict__ qh, const ushort* __restrict__ kh,
    const ushort* __restrict__ vh, ushort* __restrict__ ao,
    float* __restrict__ Oacc, float* __restrict__ Lacc) {
  __shared__ ushort Ps[64][72];
  __shared__ ushort Vt[2][4720];
  int bid = blockIdx.x;
  int bh = bid & 31;
  int tt = 79 - (bid >> 5);  // heavy-first
  int s, c;
  if (tt < 8) {
    s = tt;
    c = 0;
  } else if (tt < 24) {
    int u = tt - 8;
    s = 8 + (u >> 1);
    c = u & 1;
  } else if (tt < 48) {
    int u = tt - 24;
    int d3 = u / 3;
    s = 16 + d3;
    c = u - 3 * d3;
  } else {
    int u = tt - 48;
    s = 24 + (u >> 2);
    c = u & 3;
  }
  int q0 = s * 64;
  int kt0 = c * 8;
  int kend = kt0 + 8;
  if (kend > s + 1) kend = s + 1;
  int b = bh >> 4, h = bh & 15;
  int tid = threadIdx.x;
  int w = tid >> 6, lane = tid & 63, l16 = lane & 15, q4 = lane >> 4;

  const ushort* kbase = kh + (size_t)bh * SS * HDM;
  const ushort* vbase = vh + (size_t)bh * SS * HDM;

  short8 qf[2][2];
#pragma unroll
  for (int qi = 0; qi < 2; ++qi) {
    const ushort* qrow =
        qh + ((size_t)bh * SS + q0 + 32 * w + 16 * qi + l16) * HDM;
    qf[qi][0] = *(const short8*)(qrow + 8 * q4);
    qf[qi][1] = *(const short8*)(qrow + 32 + 8 * q4);
  }

  int so8 = tid & 7, sp = (tid >> 3) & 15;

  short8 kf[4][2];
#pragma unroll
  for (int ki = 0; ki < 4; ++ki) {
    const ushort* kr = kbase + (size_t)(kt0 * 64 + 16 * ki + l16) * HDM + 8 * q4;
    kf[ki][0] = *(const short8*)(kr);
    kf[ki][1] = *(const short8*)(kr + 32);
  }
  uint4 vr[4];
#pragma unroll
  for (int j = 0; j < 4; ++j)
    vr[j] =
        *(const uint4*)(vbase + (size_t)(kt0 * 64 + 4 * sp + j) * HDM + 8 * so8);
#pragma unroll
  for (int j = 0; j < 4; j += 2) {
    const ushort* pa = (const ushort*)&vr[j];
    const ushort* pb = (const ushort*)&vr[j + 1];
#pragma unroll
    for (int dd = 0; dd < 8; ++dd) {
      int d = so8 * 8 + dd;
      *(unsigned*)&Vt[0][VT_IDX(d, 4 * sp + j)] =
          (unsigned)pa[dd] | ((unsigned)pb[dd] << 16);
    }
  }
  __syncthreads();

  floatx4 o[4][2];
#pragma unroll
  for (int di = 0; di < 4; ++di)
#pragma unroll
    for (int qi = 0; qi < 2; ++qi) o[di][qi] = 0;
  float l_part[2] = {0.f, 0.f};

  for (int kt = kt0; kt < kend; ++kt) {
    int buf = (kt - kt0) & 1;
    bool has_next = (kt + 1) < kend;
    short8 kn[4][2];
    if (has_next) {
      int k0n = (kt + 1) * 64;
#pragma unroll
      for (int ki = 0; ki < 4; ++ki) {
        const ushort* kr = kbase + (size_t)(k0n + 16 * ki + l16) * HDM + 8 * q4;
        kn[ki][0] = *(const short8*)(kr);
        kn[ki][1] = *(const short8*)(kr + 32);
      }
#pragma unroll
      for (int j = 0; j < 4; ++j)
        vr[j] =
            *(const uint4*)(vbase + (size_t)(k0n + 4 * sp + j) * HDM + 8 * so8);
    }

    floatx4 s4[2][4];
#pragma unroll
    for (int ki = 0; ki < 4; ++ki)
#pragma unroll
      for (int qi = 0; qi < 2; ++qi) {
        floatx4 cc;
        cc = 0;
        cc = __builtin_amdgcn_mfma_f32_16x16x32_bf16(kf[ki][0], qf[qi][0], cc,
                                                     0, 0, 0);
        cc = __builtin_amdgcn_mfma_f32_16x16x32_bf16(kf[ki][1], qf[qi][1], cc,
                                                     0, 0, 0);
        s4[qi][ki] = cc;
      }

    bool diag = (kt == s);  // tile containing the causal boundary (k0 == q0)
#pragma unroll
    for (int qi = 0; qi < 2; ++qi) {
      int qloc = 32 * w + 16 * qi + l16;
      float lp = 0.f;
#pragma unroll
      for (int ki = 0; ki < 4; ++ki) {
        float p[4];
#pragma unroll
        for (int r = 0; r < 4; ++r) {
          float t = s4[qi][ki][r] * 0.18033688f;
          float pv = exp2f(t);
          if (diag && (16 * ki + 4 * q4 + r) > qloc) pv = 0.f;
          p[r] = pv;
          lp += pv;
        }
        uint2 u2;
        u2.x = pack_bf_trunc(p[0], p[1]);
        u2.y = pack_bf_trunc(p[2], p[3]);
        *(uint2*)&Ps[qloc][16 * ki + 4 * q4] = u2;
      }
      l_part[qi] += lp;
    }

#pragma unroll
    for (int qi = 0; qi < 2; ++qi) {
      short8 pf0 = *(const short8*)&Ps[32 * w + 16 * qi + l16][8 * q4];
      short8 pf1 = *(const short8*)&Ps[32 * w + 16 * qi + l16][32 + 8 * q4];
#pragma unroll
      for (int di = 0; di < 4; ++di) {
        short8 vf0 = *(const short8*)&Vt[buf][VT_IDX(16 * di + l16, 8 * q4)];
        short8 vf1 =
            *(const short8*)&Vt[buf][VT_IDX(16 * di + l16, 32 + 8 * q4)];
        o[di][qi] =
            __builtin_amdgcn_mfma_f32_16x16x32_bf16(vf0, pf0, o[di][qi], 0, 0, 0);
        o[di][qi] =
            __builtin_amdgcn_mfma_f32_16x16x32_bf16(vf1, pf1, o[di][qi], 0, 0, 0);
      }
    }

    if (has_next) {
      int nb = (kt + 1 - kt0) & 1;
#pragma unroll
      for (int j = 0; j < 4; j += 2) {
        const ushort* pa = (const ushort*)&vr[j];
        const ushort* pb = (const ushort*)&vr[j + 1];
#pragma unroll
        for (int dd = 0; dd < 8; ++dd) {
          int d = so8 * 8 + dd;
          *(unsigned*)&Vt[nb][VT_IDX(d, 4 * sp + j)] =
              (unsigned)pa[dd] | ((unsigned)pb[dd] << 16);
        }
      }
#pragma unroll
      for (int ki = 0; ki < 4; ++ki) {
        kf[ki][0] = kn[ki][0];
        kf[ki][1] = kn[ki][1];
      }
    }
    __syncthreads();
  }

  // reduce l across q4 groups (lanes sharing l16)
#pragma unroll
  for (int qi = 0; qi < 2; ++qi) {
    float l = l_part[qi];
    l += __shfl_xor(l, 16);
    l += __shfl_xor(l, 32);
    l_part[qi] = l;
  }

  if (s < 8) {
    // single chunk: final result, write bf16 directly
#pragma unroll
    for (int qi = 0; qi < 2; ++qi) {
      float inv = 1.0f / l_part[qi];
      int token = q0 + 32 * w + 16 * qi + l16;
      ushort* orow = ao + ((size_t)(b * SS + token)) * DD + h * HDM;
#pragma unroll
      for (int di = 0; di < 4; ++di) {
        floatx4 ov = o[di][qi];
        uint2 u2;
        u2.x = pack_bf_rne(ov[0] * inv, ov[1] * inv);
        u2.y = pack_bf_rne(ov[2] * inv, ov[3] * inv);
        *(uint2*)&orow[16 * di + 4 * q4] = u2;
      }
    }
  } else {
    // partial: accumulate into Oacc/Lacc
    float* Ob = Oacc + (size_t)bh * 64 * SS;
#pragma unroll
    for (int qi = 0; qi < 2; ++qi) {
      int token = q0 + 32 * w + 16 * qi + l16;
      if (q4 == 0) atomicAdd(&Lacc[bh * SS + token], l_part[qi]);
#pragma unroll
      for (int di = 0; di < 4; ++di) {
#pragma unroll
        for (int r = 0; r < 4; ++r)
          atomicAdd(&Ob[(size_t)(16 * di + 4 * q4 + r) * SS + token],
                    o[di][qi][r]);
      }
    }
  }
}

// ---------------------------------------------------------------------------
// attn_norm: normalize accumulated partials for tokens >= 512.
// grid (12, 32): blockIdx.x = stile-4 (tokens 512..2047), blockIdx.y = bh
// ---------------------------------------------------------------------------
__global__ __launch_bounds__(256) void attn_norm(
    const float* __restrict__ Oacc, const float* __restrict__ Lacc,
    ushort* __restrict__ ao) {
  __shared__ float tile[64][129];
  int bh = blockIdx.y;
  int s0 = (blockIdx.x + 4) * 128;
  int b = bh >> 4, h = bh & 15;
  int tid = threadIdx.x;
  const float* Ob = Oacc + (size_t)bh * 64 * SS;
#pragma unroll
  for (int i = 0; i < 32; ++i) {
    int idx = i * 256 + tid;
    int d = idx >> 7, tok = idx & 127;
    tile[d][tok] = Ob[(size_t)d * SS + s0 + tok];
  }
  __syncthreads();
#pragma unroll
  for (int i = 0; i < 2; ++i) {
    int u = i * 256 + tid;
    int tok = u >> 2, qtr = u & 3;
    float inv = 1.0f / Lacc[bh * SS + s0 + tok];
    ushort* orow = ao + ((size_t)(b * SS + s0 + tok)) * DD + h * HDM + qtr * 16;
    uint2 u2a, u2b;
    u2a.x = pack_bf_rne(tile[qtr * 16 + 0][tok] * inv,
                        tile[qtr * 16 + 1][tok] * inv);
    u2a.y = pack_bf_rne(tile[qtr * 16 + 2][tok] * inv,
                        tile[qtr * 16 + 3][tok] * inv);
    *(uint2*)&orow[0] = u2a;
    u2a.x = pack_bf_rne(tile[qtr * 16 + 4][tok] * inv,
                        tile[qtr * 16 + 5][tok] * inv);
    u2a.y = pack_bf_rne(tile[qtr * 16 + 6][tok] * inv,
                        tile[qtr * 16 + 7][tok] * inv);
    *(uint2*)&orow[4] = u2a;
    u2b.x = pack_bf_rne(tile[qtr * 16 + 8][tok] * inv,
                        tile[qtr * 16 + 9][tok] * inv);
    u2b.y = pack_bf_rne(tile[qtr * 16 + 10][tok] * inv,
                        tile[qtr * 16 + 11][tok] * inv);
    *(uint2*)&orow[8] = u2b;
    u2b.x = pack_bf_rne(tile[qtr * 16 + 12][tok] * inv,
                        tile[qtr * 16 + 13][tok] * inv);
    u2b.y = pack_bf_rne(tile[qtr * 16 + 14][tok] * inv,
                        tile[qtr * 16 + 15][tok] * inv);
    *(uint2*)&orow[12] = u2b;
  }
}

// ---------------------------------------------------------------------------
// gemm_out (unchanged)
// ---------------------------------------------------------------------------
__global__ __launch_bounds__(256) void gemm_out(
    const ushort* __restrict__ A, const ushort* __restrict__ Bt,
    const float* __restrict__ bias, float* __restrict__ C) {
  __shared__ ushort As[64][40];
  __shared__ ushort Bs[128][40];
  int tid = threadIdx.x;
  int bm = blockIdx.x * 64, bn = blockIdx.y * 128;
  int w = tid >> 6, lane = tid & 63, l16 = lane & 15, q4 = lane >> 4;
  int wm = (w >> 1) * 32, wn = (w & 1) * 64;
  floatx4 acc[2][4];
#pragma unroll
  for (int mi = 0; mi < 2; ++mi)
#pragma unroll
    for (int ni = 0; ni < 4; ++ni) acc[mi][ni] = 0;

  int sr = tid >> 2, sc = (tid & 3) * 8;
  const ushort* Ap0 = A + (size_t)(bm + sr) * DD + sc;
  const ushort* Bp0 = Bt + (size_t)(bn + sr) * DD + sc;
  const ushort* Bp1 = Bt + (size_t)(bn + sr + 64) * DD + sc;

  for (int k0 = 0; k0 < DD; k0 += 32) {
    uint4 a0 = *(const uint4*)(Ap0 + k0);
    uint4 b0 = *(const uint4*)(Bp0 + k0);
    uint4 b1 = *(const uint4*)(Bp1 + k0);
    __syncthreads();
    *(uint4*)&As[sr & 63][sc] = a0;
    *(uint4*)&Bs[sr][sc] = b0;
    *(uint4*)&Bs[sr + 64][sc] = b1;
    __syncthreads();
    short8 af[2], bf[4];
#pragma unroll
    for (int mi = 0; mi < 2; ++mi)
      af[mi] = *(const short8*)&As[wm + mi * 16 + l16][q4 * 8];
#pragma unroll
    for (int ni = 0; ni < 4; ++ni)
      bf[ni] = *(const short8*)&Bs[wn + ni * 16 + l16][q4 * 8];
#pragma unroll
    for (int mi = 0; mi < 2; ++mi)
#pragma unroll
      for (int ni = 0; ni < 4; ++ni)
        acc[mi][ni] = __builtin_amdgcn_mfma_f32_16x16x32_bf16(
            af[mi], bf[ni], acc[mi][ni], 0, 0, 0);
  }
#pragma unroll
  for (int mi = 0; mi < 2; ++mi) {
#pragma unroll
    for (int r = 0; r < 4; ++r) {
      int row = bm + wm + mi * 16 + q4 * 4 + r;
      float* Cr = C + (size_t)row * DD;
#pragma unroll
      for (int ni = 0; ni < 4; ++ni) {
        int col = bn + wn + ni * 16 + l16;
        Cr[col] = acc[mi][ni][r] + bias[col];
      }
    }
  }
}

// ---------------------------------------------------------------------------
extern "C" void kernel_launch(void* const* d_in, const int* in_sizes, int n_in,
                              void* d_out, int out_size, void* d_ws,
                              size_t ws_size, hipStream_t stream) {
  const float* x    = (const float*)d_in[0];
  const float* Wq   = (const float*)d_in[1];
  const float* bq   = (const float*)d_in[2];
  const float* Wo   = (const float*)d_in[3];
  const float* bo   = (const float*)d_in[4];
  const float* Wk   = (const float*)d_in[5];
  const float* bk   = (const float*)d_in[6];
  const float* kw1  = (const float*)d_in[7];
  const float* kb1  = (const float*)d_in[8];
  const float* kw2  = (const float*)d_in[9];
  const float* kb2  = (const float*)d_in[10];
  const float* kgAw = (const float*)d_in[11];
  const float* kgAb = (const float*)d_in[12];
  const float* kgBw = (const float*)d_in[13];
  const float* kgBb = (const float*)d_in[14];
  const float* Wv   = (const float*)d_in[15];
  const float* bv   = (const float*)d_in[16];
  const float* vw1  = (const float*)d_in[17];
  const float* vb1  = (const float*)d_in[18];
  const float* vw2  = (const float*)d_in[19];
  const float* vb2  = (const float*)d_in[20];
  const float* vgAw = (const float*)d_in[21];
  const float* vgAb = (const float*)d_in[22];
  const float* vgBw = (const float*)d_in[23];
  const float* vgBb = (const float*)d_in[24];
  float* out = (float*)d_out;

  char* ws = (char*)d_ws;
  const size_t MB = 1024 * 1024;
  // layout: live-late buffers low so the Oacc tail region (dead-alias) works
  ushort* qhb  = (ushort*)(ws);            // 0-8
  ushort* khb  = (ushort*)(ws + 8 * MB);   // 8-16
  ushort* vhb  = (ushort*)(ws + 16 * MB);  // 16-24
  ushort* xb   = (ushort*)(ws + 24 * MB);  // 24-32 (dead after gemm_qkv)
  ushort* Wto  = (ushort*)(ws + 32 * MB);  // 32-34 (live till gemm_out)
  ushort* aob2 = (ushort*)(ws + 34 * MB);  // 34-42 (attn out)
  ushort* Wcat = (ushort*)(ws + 42 * MB);  // 42-52 (dead after gemm_qkv)
  ushort* Wtk  = (ushort*)(ws + 52 * MB);  // 52-54 (dead after weff)
  ushort* Wtv  = (ushort*)(ws + 54 * MB);  // 54-56
  float*  Ak   = (float*)(ws + 56 * MB);
  float*  Bk   = Ak + BB * RNK * DD;
  float*  Av   = Bk + BB * RNK * DD;
  float*  Bv   = Av + BB * RNK * DD;
  float*  zsum = Bv + BB * RNK * DD;
  float*  h_pre = zsum + BB * DD;
  float*  c_all = h_pre + 4 * 256;
  float2* tab  = (float2*)(ws + 56 * MB + 512 * 1024);  // ends at 57 MB
  // split-K accumulators at the TAIL of ws (requires ws_size >= ~59 MB);
  // zeroed after gemm_qkv so aliasing then-dead regions (Wcat/Wtk/Wtv) is OK
  size_t ooff = (ws_size - 17 * MB) & ~(size_t)255;
  float* Oacc = (float*)(ws + ooff);            // 16 MB: [bh][64d][2048s]
  float* Lacc = (float*)(ws + ooff + 16 * MB);  // 256 KB: [bh][2048s]

  hipMemsetAsync(zsum, 0, (BB * DD + 4 * 256) * sizeof(float), stream);
  prep_all<<<8704, 256, 0, stream>>>(x, Wq, Wk, Wv, Wo, xb, Wcat, Wtk, Wtv,
                                     Wto, tab, zsum);
  gen_h<<<dim3(4, 8), 256, 0, stream>>>(zsum, kw1, vw1, h_pre);
  hyper_c2<<<4, 256, 0, stream>>>(h_pre, kb1, kw2, kb2, vb1, vw2, vb2, c_all);
  gen_AB<<<dim3(RNK * DD / 256, 4), 256, 0, stream>>>(
      c_all, kgAw, kgAb, kgBw, kgBb, vgAw, vgAb, vgBw, vgBb, Ak, Bk, Av, Bv);
  weff<<<dim3(64, 4), 256, 0, stream>>>(Ak, Bk, Av, Bv, Wtk, Wtv, Wcat);

  gemm_qkv<<<dim3(32, 24), 256, 0, stream>>>(xb, Wcat, bq, bk, bv, tab, qhb,
                                             khb, vhb);
  // zero split-K accumulators (Wcat/Wtk/Wtv now dead; safe to alias)
  hipMemsetAsync(Oacc, 0, 16 * MB + (size_t)BB * NH * SS * sizeof(float),
                 stream);
  attn_split<<<2560, 128, 0, stream>>>(qhb, khb, vhb, aob2, Oacc, Lacc);
  attn_norm<<<dim3(12, 32), 256, 0, stream>>>(Oacc, Lacc, aob2);
  gemm_out<<<dim3(64, 8), 256, 0, stream>>>(aob2, Wto, bo, out);
}